// Round 5
// baseline (558.090 us; speedup 1.0000x reference)
//
#include <hip/hip_runtime.h>
#include <hip/hip_bf16.h>
#include <math.h>

#define DM 256      // D_MODEL
#define NL 4        // N_LAYERS
#define DI 512      // D_INNER
#define DS 16       // D_STATE
#define DC 4        // D_CONV
#define DR 16       // DT_RANK
#define NC 10       // NUM_CLASSES
#define NB 8        // B
#define LL 1024     // L
#define MR (NB*LL)  // 8192 rows
#define NCHUNK 64
#define CLEN 16

typedef __attribute__((ext_vector_type(4))) float f32x4;
typedef __attribute__((ext_vector_type(8))) short short8;

__device__ __forceinline__ float silu_f(float x) {
    return x * (1.0f / (1.0f + __expf(-x)));
}
__device__ __forceinline__ float bf2f(ushort v) {
    union { unsigned u; float f; } c; c.u = ((unsigned)v) << 16; return c.f;
}
__device__ __forceinline__ ushort f2bf(float f) {   // round-to-nearest-even
    union { float f; unsigned u; } c; c.f = f;
    unsigned lsb = (c.u >> 16) & 1;
    return (ushort)((c.u + 0x7fffu + lsb) >> 16);
}
__device__ __forceinline__ void g2lds16(const void* g, void* l) {
    __builtin_amdgcn_global_load_lds((const __attribute__((address_space(1))) void*)g,
                                     (__attribute__((address_space(3))) void*)l, 16, 0, 0);
}

// ---- weight fp32 -> bf16 conversion (x_proj padded 48 -> 64 rows) ----
#define IPW_N (NL*2*DI*DM)   // 1048576
#define XPW_N (NL*64*DI)     // 131072 (padded)
#define OPW_N (NL*DM*DI)     // 524288
__global__ __launch_bounds__(256) void convert_weights_kernel(
        const float* __restrict__ ipw, const float* __restrict__ xpw,
        const float* __restrict__ opw,
        ushort* __restrict__ ipw_b, ushort* __restrict__ xpw_b, ushort* __restrict__ opw_b) {
    int t = blockIdx.x * 256 + threadIdx.x;
    if (t < IPW_N) { ipw_b[t] = f2bf(ipw[t]); return; }
    t -= IPW_N;
    if (t < XPW_N) {
        int l = t >> 15, r = (t >> 9) & 63, k = t & 511;
        xpw_b[t] = (r < 48) ? f2bf(xpw[((size_t)l * 48 + r) * DI + k]) : (ushort)0;
        return;
    }
    t -= XPW_N;
    if (t < OPW_N) opw_b[t] = f2bf(opw[t]);
}

// h[m][d] = x[m] * w[d] + b[d]  (fp32 residual stream init)
__global__ void input_proj_kernel(const float* __restrict__ x, const float* __restrict__ w,
                                  const float* __restrict__ b, float* __restrict__ h) {
    int t = blockIdx.x * 256 + threadIdx.x;
    if (t >= MR * DM) return;
    int d = t & (DM - 1);
    int m = t >> 8;
    h[t] = x[m] * w[d] + b[d];
}

// layernorm over 256 cols, bf16 output
__global__ __launch_bounds__(256) void layernorm_bf16_kernel(const float* __restrict__ in,
        const float* __restrict__ w, const float* __restrict__ b, ushort* __restrict__ out) {
    int row = blockIdx.x, t = threadIdx.x;
    float v = in[row * DM + t];
    float s = v, q = v * v;
#pragma unroll
    for (int o = 32; o >= 1; o >>= 1) { s += __shfl_xor(s, o); q += __shfl_xor(q, o); }
    __shared__ float red[8];
    int wid = t >> 6;
    if ((t & 63) == 0) { red[wid] = s; red[4 + wid] = q; }
    __syncthreads();
    s = red[0] + red[1] + red[2] + red[3];
    q = red[4] + red[5] + red[6] + red[7];
    float mu = s * (1.0f / DM);
    float var = q * (1.0f / DM) - mu * mu;
    float rs = rsqrtf(var + 1e-5f);
    out[row * DM + t] = f2bf((v - mu) * rs * w[t] + b[t]);
}

// ---- bf16 MFMA GEMM: C[M,N] = A[M,K] @ W[N,K]^T ----
// MODE 0: bf16 out + bias; MODE 1: f32 out; MODE 2: f32 out += acc + bias
template<int BM, int BN, int WM, int WN, int MODE>
__global__ __launch_bounds__(256) void mfma_gemm_kernel(
        const ushort* __restrict__ A, int lda,
        const ushort* __restrict__ W,
        const float* __restrict__ bias,
        ushort* __restrict__ Cb, float* __restrict__ Cf, int ldc, int K) {
    constexpr int FM = BM / WM / 16;
    constexpr int FN = BN / WN / 16;
    __shared__ __align__(16) char smem[(BM + BN) * 128];
    const int tid = threadIdx.x;
    const int l = tid & 63, w = tid >> 6;
    const int wr = w / WN, wc = w % WN;
    const int bm = blockIdx.x * BM, bn = blockIdx.y * BN;
    const int ldw = K;

    f32x4 acc[FM][FN] = {};

    for (int k0 = 0; k0 < K; k0 += 64) {
#pragma unroll
        for (int i = 0; i < (BM * 128 / 16) / 256; i++) {
            int lin = (i * 256 + tid) * 16;
            int q = lin ^ (((lin >> 7) & 7) << 4);
            g2lds16(A + (size_t)(bm + (q >> 7)) * lda + k0 + ((q & 127) >> 1), smem + lin);
        }
#pragma unroll
        for (int i = 0; i < (BN * 128 / 16) / 256; i++) {
            int lin = (i * 256 + tid) * 16;
            int q = lin ^ (((lin >> 7) & 7) << 4);
            g2lds16(W + (size_t)(bn + (q >> 7)) * ldw + k0 + ((q & 127) >> 1),
                    smem + BM * 128 + lin);
        }
        __syncthreads();
        const int rl = l & 15;
        const int kb0 = ((l >> 4) << 3) * 2;
#pragma unroll
        for (int kk = 0; kk < 2; kk++) {
            short8 af[FM], bfr[FN];
#pragma unroll
            for (int m = 0; m < FM; m++) {
                int off = (wr * (BM / WM) + m * 16 + rl) * 128 + kk * 64 + kb0;
                off ^= ((off >> 7) & 7) << 4;
                af[m] = *(const short8*)(smem + off);
            }
#pragma unroll
            for (int n = 0; n < FN; n++) {
                int off = (wc * (BN / WN) + n * 16 + rl) * 128 + kk * 64 + kb0;
                off ^= ((off >> 7) & 7) << 4;
                bfr[n] = *(const short8*)(smem + BM * 128 + off);
            }
#pragma unroll
            for (int m = 0; m < FM; m++)
#pragma unroll
                for (int n = 0; n < FN; n++)
                    acc[m][n] = __builtin_amdgcn_mfma_f32_16x16x32_bf16(
                        af[m], bfr[n], acc[m][n], 0, 0, 0);
        }
        __syncthreads();
    }

    const int row0 = bm + wr * (BM / WM) + ((l >> 4) << 2);
    const int col0 = bn + wc * (BN / WN) + (l & 15);
#pragma unroll
    for (int m = 0; m < FM; m++) {
#pragma unroll
        for (int n = 0; n < FN; n++) {
            int col = col0 + n * 16;
            float bv = (MODE == 1) ? 0.f : bias[col];
#pragma unroll
            for (int r = 0; r < 4; r++) {
                size_t idx = (size_t)(row0 + m * 16 + r) * ldc + col;
                float v = acc[m][n][r];
                if (MODE == 0) Cb[idx] = f2bf(v + bv);
                else if (MODE == 1) Cf[idx] = v;
                else Cf[idx] += v + bv;
            }
        }
    }
}

// depthwise causal conv (K=4) + SiLU; xz bf16 (ld 1024, cols 0..511) -> u bf16
__global__ __launch_bounds__(256) void conv_silu_kernel(const ushort* __restrict__ xz,
        const float* __restrict__ cw, const float* __restrict__ cb, ushort* __restrict__ u) {
    int t = blockIdx.x * 256 + threadIdx.x;   // MR*DI/8 threads
    int d8 = (t & 63) << 3;
    int m = t >> 6;
    int l = m & (LL - 1);
    const short8 zr = {0, 0, 0, 0, 0, 0, 0, 0};
    const size_t base = (size_t)m * 1024 + d8;
    short8 r3 = *(const short8*)(xz + base);
    short8 r2 = (l >= 1) ? *(const short8*)(xz + base - 1024) : zr;
    short8 r1 = (l >= 2) ? *(const short8*)(xz + base - 2048) : zr;
    short8 r0 = (l >= 3) ? *(const short8*)(xz + base - 3072) : zr;
    short8 o;
#pragma unroll
    for (int j = 0; j < 8; j++) {
        int d = d8 + j;
        float4 w4 = *reinterpret_cast<const float4*>(&cw[d * 4]);
        float a = cb[d] + w4.w * bf2f((ushort)r3[j]);
        a += w4.z * bf2f((ushort)r2[j]);
        a += w4.y * bf2f((ushort)r1[j]);
        a += w4.x * bf2f((ushort)r0[j]);
        o[j] = (short)f2bf(silu_f(a));
    }
    *(short8*)(u + (size_t)m * DI + d8) = o;
}

// ---- chunked parallel scan; u bf16, x_dbl f32 ld 64, delta computed inline ----
// delta[m][d] = softplus( x_dbl[m][0..15] . dtw[d][:] + dtb[d] )
// Phase 1: per (b,c,d) thread: chunk state S (from h=0) and sdv = sum(delta).
__global__ __launch_bounds__(256, 4) void scan_phase1_kernel(
        const ushort* __restrict__ u, const float* __restrict__ x_dbl,
        const float* __restrict__ A_log,
        const float* __restrict__ dtw, const float* __restrict__ dtb,
        float* __restrict__ sdv, float* __restrict__ Sbuf) {
    int gid = blockIdx.x * 256 + threadIdx.x;
    int d = gid & (DI - 1);
    int c = (gid >> 9) & (NCHUNK - 1);
    int b = gid >> 15;
    float Aval[DS], h[DS], wreg[DR];
#pragma unroll
    for (int q = 0; q < 4; q++) {
        float4 a4 = *reinterpret_cast<const float4*>(&A_log[d * DS + q * 4]);
        Aval[q*4+0] = -__expf(a4.x); Aval[q*4+1] = -__expf(a4.y);
        Aval[q*4+2] = -__expf(a4.z); Aval[q*4+3] = -__expf(a4.w);
        float4 w4 = *reinterpret_cast<const float4*>(&dtw[d * DR + q * 4]);
        wreg[q*4] = w4.x; wreg[q*4+1] = w4.y; wreg[q*4+2] = w4.z; wreg[q*4+3] = w4.w;
    }
    float dbv = dtb[d];
#pragma unroll
    for (int n = 0; n < DS; n++) h[n] = 0.f;
    int m0 = b * LL + c * CLEN;
    const float* xb = x_dbl + (size_t)m0 * 64;   // wave-uniform rows
    const ushort* up = u + (size_t)m0 * DI + d;
    float sd = 0.f;
    float uv = bf2f(up[0]);
    for (int t = 0; t < CLEN; t++) {
        float uvn = (t + 1 < CLEN) ? bf2f(up[(size_t)(t + 1) * DI]) : 0.f;
        const float* xr = xb + (size_t)t * 64;
        // inline dt_proj + softplus (tree-reduced dot)
        float p0 = dbv, p1 = 0.f, p2 = 0.f, p3 = 0.f;
#pragma unroll
        for (int k = 0; k < 4; k++) {
            p0 += wreg[k] * xr[k];
            p1 += wreg[4 + k] * xr[4 + k];
            p2 += wreg[8 + k] * xr[8 + k];
            p3 += wreg[12 + k] * xr[12 + k];
        }
        float z = (p0 + p1) + (p2 + p3);
        float dv = (z > 20.0f) ? z : __logf(1.0f + __expf(z));
        sd += dv;
        float du = dv * uv;
#pragma unroll
        for (int n = 0; n < DS; n++) {
            float dA = __expf(dv * Aval[n]);
            h[n] = dA * h[n] + du * xr[16 + n];
        }
        uv = uvn;
    }
    size_t base = ((size_t)((b * NCHUNK + c) * DI + d)) * DS;
#pragma unroll
    for (int q = 0; q < 4; q++)
        *reinterpret_cast<float4*>(&Sbuf[base + q * 4]) =
            make_float4(h[q*4], h[q*4+1], h[q*4+2], h[q*4+3]);
    sdv[(b * NCHUNK + c) * DI + d] = sd;
}

// Phase 2: per (b,d,n) thread; P_c = exp(A*sdv_c); Sbuf[c] overwritten with hinit.
__global__ __launch_bounds__(256) void scan_phase2_kernel(
        const float* __restrict__ sdv, const float* __restrict__ A_log,
        float* __restrict__ Sbuf) {
    int gid = blockIdx.x * 256 + threadIdx.x;
    int dn = gid & (DI * DS - 1);
    int b = gid >> 13;
    int n = dn & 15, d = dn >> 4;
    float Aval = -__expf(A_log[d * DS + n]);
    size_t idx0 = (size_t)b * NCHUNK * DI * DS + dn;
    const size_t stride = (size_t)DI * DS;
    int sb0 = b * NCHUNK * DI + d;
    float h = 0.f;
    float Sc = Sbuf[idx0];
    float sd = sdv[sb0];
    for (int c = 0; c < NCHUNK; c++) {
        size_t idx = idx0 + (size_t)c * stride;
        float Sn = 0.f, sdn = 0.f;
        if (c + 1 < NCHUNK) {
            Sn = Sbuf[idx + stride];
            sdn = sdv[sb0 + (c + 1) * DI];
        }
        float Pc = __expf(Aval * sd);
        Sbuf[idx] = h;
        h = Pc * h + Sc;
        Sc = Sn; sd = sdn;
    }
}

// Phase 3 + fused gate: replay chunk from hinit, y = scan_y * silu(res), bf16 out
__global__ __launch_bounds__(256, 4) void scan_phase3_kernel(
        const ushort* __restrict__ u, const float* __restrict__ x_dbl,
        const float* __restrict__ A_log,
        const float* __restrict__ dtw, const float* __restrict__ dtb,
        const float* __restrict__ Dp, const float* __restrict__ Sbuf,
        const ushort* __restrict__ xz, ushort* __restrict__ y) {
    int gid = blockIdx.x * 256 + threadIdx.x;
    int d = gid & (DI - 1);
    int c = (gid >> 9) & (NCHUNK - 1);
    int b = gid >> 15;
    float Aval[DS], h[DS], wreg[DR];
#pragma unroll
    for (int q = 0; q < 4; q++) {
        float4 a4 = *reinterpret_cast<const float4*>(&A_log[d * DS + q * 4]);
        Aval[q*4+0] = -__expf(a4.x); Aval[q*4+1] = -__expf(a4.y);
        Aval[q*4+2] = -__expf(a4.z); Aval[q*4+3] = -__expf(a4.w);
        float4 w4 = *reinterpret_cast<const float4*>(&dtw[d * DR + q * 4]);
        wreg[q*4] = w4.x; wreg[q*4+1] = w4.y; wreg[q*4+2] = w4.z; wreg[q*4+3] = w4.w;
    }
    float dbv = dtb[d];
    size_t base = ((size_t)((b * NCHUNK + c) * DI + d)) * DS;
#pragma unroll
    for (int q = 0; q < 4; q++) {
        float4 h4 = *reinterpret_cast<const float4*>(&Sbuf[base + q * 4]);
        h[q*4] = h4.x; h[q*4+1] = h4.y; h[q*4+2] = h4.z; h[q*4+3] = h4.w;
    }
    float Dval = Dp[d];
    int m0 = b * LL + c * CLEN;
    const float* xb = x_dbl + (size_t)m0 * 64;   // wave-uniform rows
    const ushort* up = u + (size_t)m0 * DI + d;
    const ushort* rp = xz + (size_t)m0 * 1024 + 512 + d;
    ushort* yp = y + (size_t)m0 * DI + d;
    float uv = bf2f(up[0]);
    float rv = bf2f(rp[0]);
    for (int t = 0; t < CLEN; t++) {
        float uvn = 0.f, rvn = 0.f;
        if (t + 1 < CLEN) {
            uvn = bf2f(up[(size_t)(t + 1) * DI]);
            rvn = bf2f(rp[(size_t)(t + 1) * 1024]);
        }
        const float* xr = xb + (size_t)t * 64;
        float p0 = dbv, p1 = 0.f, p2 = 0.f, p3 = 0.f;
#pragma unroll
        for (int k = 0; k < 4; k++) {
            p0 += wreg[k] * xr[k];
            p1 += wreg[4 + k] * xr[4 + k];
            p2 += wreg[8 + k] * xr[8 + k];
            p3 += wreg[12 + k] * xr[12 + k];
        }
        float z = (p0 + p1) + (p2 + p3);
        float dv = (z > 20.0f) ? z : __logf(1.0f + __expf(z));
        float du = dv * uv;
        float a0 = 0.f, a1 = 0.f, a2 = 0.f, a3 = 0.f;
#pragma unroll
        for (int j = 0; j < 4; j++) {
            {
                int n = j;
                float dA = __expf(dv * Aval[n]);
                h[n] = dA * h[n] + du * xr[16 + n];
                a0 += h[n] * xr[32 + n];
            }
            {
                int n = 4 + j;
                float dA = __expf(dv * Aval[n]);
                h[n] = dA * h[n] + du * xr[16 + n];
                a1 += h[n] * xr[32 + n];
            }
            {
                int n = 8 + j;
                float dA = __expf(dv * Aval[n]);
                h[n] = dA * h[n] + du * xr[16 + n];
                a2 += h[n] * xr[32 + n];
            }
            {
                int n = 12 + j;
                float dA = __expf(dv * Aval[n]);
                h[n] = dA * h[n] + du * xr[16 + n];
                a3 += h[n] * xr[32 + n];
            }
        }
        float acc = ((a0 + a1) + (a2 + a3)) + Dval * uv;
        yp[(size_t)t * DI] = f2bf(acc * silu_f(rv));
        uv = uvn; rv = rvn;
    }
}

// pool stage 1: partial[(b*8+slice)][dm] = sum over 128 l's
__global__ __launch_bounds__(256) void pool_partial_kernel(const ushort* __restrict__ ln,
                                                           float* __restrict__ partial) {
    int bs = blockIdx.x;            // 0..63
    int b = bs >> 3, sl = bs & 7;
    int t = threadIdx.x;            // dm
    int l0 = sl * 128;
    float s = 0.f;
    for (int l = 0; l < 128; l++) s += bf2f(ln[(size_t)(b * LL + l0 + l) * DM + t]);
    partial[(bs << 8) + t] = s;
}

__global__ void cls_kernel(const float* __restrict__ partial, const float* __restrict__ cw,
                           const float* __restrict__ cb, float* __restrict__ out) {
    int t = threadIdx.x;
    if (t >= NB * NC) return;
    int b = t / NC, c = t % NC;
    float s = 0.f;
    for (int k = 0; k < DM; k++) {
        float p = 0.f;
#pragma unroll
        for (int sl = 0; sl < 8; sl++) p += partial[((b * 8 + sl) << 8) + k];
        s += p * cw[c * DM + k];
    }
    out[t] = cb[c] + s * (1.0f / LL);
}

extern "C" void kernel_launch(void* const* d_in, const int* in_sizes, int n_in,
                              void* d_out, int out_size, void* d_ws, size_t ws_size,
                              hipStream_t stream) {
    const float* x       = (const float*)d_in[0];
    const float* input_w = (const float*)d_in[1];
    const float* input_b = (const float*)d_in[2];
    const float* ln_w    = (const float*)d_in[3];
    const float* ln_b    = (const float*)d_in[4];
    const float* ipw     = (const float*)d_in[5];
    const float* ipb     = (const float*)d_in[6];
    const float* cw      = (const float*)d_in[7];
    const float* cb      = (const float*)d_in[8];
    const float* xpw     = (const float*)d_in[9];
    const float* dtw     = (const float*)d_in[10];
    const float* dtb     = (const float*)d_in[11];
    const float* A_log   = (const float*)d_in[12];
    const float* Dp      = (const float*)d_in[13];
    const float* opw     = (const float*)d_in[14];
    const float* opb     = (const float*)d_in[15];
    const float* norm_w  = (const float*)d_in[16];
    const float* norm_b  = (const float*)d_in[17];
    const float* cls_w   = (const float*)d_in[18];
    const float* cls_b   = (const float*)d_in[19];
    float* out = (float*)d_out;
    float* ws = (float*)d_ws;

    float*  hres   = ws;                                   // MR*DM f32
    ushort* xz     = (ushort*)(hres + (size_t)MR * DM);    // MR*1024 bf16
    ushort* ub     = xz + (size_t)MR * 1024;               // MR*DI bf16
    float*  x_dbl  = (float*)(ub + (size_t)MR * DI);       // MR*64 f32
    float*  sdvb   = x_dbl + (size_t)MR * 64;              // NB*NCHUNK*DI f32
    float*  Sbuf   = sdvb + (size_t)NB * NCHUNK * DI;      // NB*NCHUNK*DI*DS f32
    float*  partial= Sbuf + (size_t)NB * NCHUNK * DI * DS; // 64*256 f32
    ushort* ygate  = (ushort*)(partial + 64 * 256);        // MR*DI bf16
    ushort* hln    = ygate + (size_t)MR * DI;              // MR*DM bf16
    ushort* ipw_b  = hln + (size_t)MR * DM;                // IPW_N
    ushort* xpw_b  = ipw_b + IPW_N;                        // XPW_N
    ushort* opw_b  = xpw_b + XPW_N;                        // OPW_N

    convert_weights_kernel<<<(IPW_N + XPW_N + OPW_N) / 256, 256, 0, stream>>>(
        ipw, xpw, opw, ipw_b, xpw_b, opw_b);
    input_proj_kernel<<<MR * DM / 256, 256, 0, stream>>>(x, input_w, input_b, hres);

    for (int i = 0; i < NL; i++) {
        layernorm_bf16_kernel<<<MR, 256, 0, stream>>>(hres, ln_w + i * DM, ln_b + i * DM, hln);
        mfma_gemm_kernel<128, 128, 2, 2, 0><<<dim3(MR / 128, 1024 / 128), 256, 0, stream>>>(
            hln, DM, ipw_b + (size_t)i * 2 * DI * DM, ipb + (size_t)i * 2 * DI,
            xz, nullptr, 1024, DM);
        conv_silu_kernel<<<MR * DI / 8 / 256, 256, 0, stream>>>(xz, cw + i * DI * DC, cb + i * DI, ub);
        mfma_gemm_kernel<64, 64, 4, 1, 1><<<dim3(MR / 64, 1), 256, 0, stream>>>(
            ub, DI, xpw_b + (size_t)i * 64 * DI, nullptr, nullptr, x_dbl, 64, DI);
        scan_phase1_kernel<<<NB * NCHUNK * DI / 256, 256, 0, stream>>>(
            ub, x_dbl, A_log + i * DI * DS, dtw + i * DI * DR, dtb + i * DI, sdvb, Sbuf);
        scan_phase2_kernel<<<NB * DI * DS / 256, 256, 0, stream>>>(
            sdvb, A_log + i * DI * DS, Sbuf);
        scan_phase3_kernel<<<NB * NCHUNK * DI / 256, 256, 0, stream>>>(
            ub, x_dbl, A_log + i * DI * DS, dtw + i * DI * DR, dtb + i * DI,
            Dp + i * DI, Sbuf, xz, ygate);
        mfma_gemm_kernel<64, 128, 2, 2, 2><<<dim3(MR / 64, DM / 128), 256, 0, stream>>>(
            ygate, DI, opw_b + (size_t)i * DM * DI, opb + (size_t)i * DM,
            nullptr, hres, DM, DI);
    }

    layernorm_bf16_kernel<<<MR, 256, 0, stream>>>(hres, norm_w, norm_b, hln);
    pool_partial_kernel<<<64, 256, 0, stream>>>(hln, partial);
    cls_kernel<<<1, 128, 0, stream>>>(partial, cls_w, cls_b, out);
}

// Round 6
// 503.097 us; speedup vs baseline: 1.1093x; 1.1093x over previous
//
#include <hip/hip_runtime.h>
#include <hip/hip_bf16.h>
#include <math.h>

#define DM 256      // D_MODEL
#define NL 4        // N_LAYERS
#define DI 512      // D_INNER
#define DS 16       // D_STATE
#define DC 4        // D_CONV
#define DR 16       // DT_RANK
#define NC 10       // NUM_CLASSES
#define NB 8        // B
#define LL 1024     // L
#define MR (NB*LL)  // 8192 rows
#define NCHUNK 64
#define CLEN 16

typedef __attribute__((ext_vector_type(4))) float f32x4;
typedef __attribute__((ext_vector_type(8))) short short8;

__device__ __forceinline__ float silu_f(float x) {
    return x * (1.0f / (1.0f + __expf(-x)));
}
__device__ __forceinline__ float bf2f(ushort v) {
    union { unsigned u; float f; } c; c.u = ((unsigned)v) << 16; return c.f;
}
__device__ __forceinline__ ushort f2bf(float f) {   // round-to-nearest-even
    union { float f; unsigned u; } c; c.f = f;
    unsigned lsb = (c.u >> 16) & 1;
    return (ushort)((c.u + 0x7fffu + lsb) >> 16);
}
__device__ __forceinline__ void g2lds16(const void* g, void* l) {
    __builtin_amdgcn_global_load_lds((const __attribute__((address_space(1))) void*)g,
                                     (__attribute__((address_space(3))) void*)l, 16, 0, 0);
}

// ---- weight fp32 -> bf16 conversion (x_proj padded 48 -> 64 rows) ----
#define IPW_N (NL*2*DI*DM)   // 1048576
#define XPW_N (NL*64*DI)     // 131072 (padded)
#define OPW_N (NL*DM*DI)     // 524288
__global__ __launch_bounds__(256) void convert_weights_kernel(
        const float* __restrict__ ipw, const float* __restrict__ xpw,
        const float* __restrict__ opw,
        ushort* __restrict__ ipw_b, ushort* __restrict__ xpw_b, ushort* __restrict__ opw_b) {
    int t = blockIdx.x * 256 + threadIdx.x;
    if (t < IPW_N) { ipw_b[t] = f2bf(ipw[t]); return; }
    t -= IPW_N;
    if (t < XPW_N) {
        int l = t >> 15, r = (t >> 9) & 63, k = t & 511;
        xpw_b[t] = (r < 48) ? f2bf(xpw[((size_t)l * 48 + r) * DI + k]) : (ushort)0;
        return;
    }
    t -= XPW_N;
    if (t < OPW_N) opw_b[t] = f2bf(opw[t]);
}

// h[m][d] = x[m] * w[d] + b[d]  (fp32 residual stream init)
__global__ void input_proj_kernel(const float* __restrict__ x, const float* __restrict__ w,
                                  const float* __restrict__ b, float* __restrict__ h) {
    int t = blockIdx.x * 256 + threadIdx.x;
    if (t >= MR * DM) return;
    int d = t & (DM - 1);
    int m = t >> 8;
    h[t] = x[m] * w[d] + b[d];
}

// layernorm over 256 cols, bf16 output
__global__ __launch_bounds__(256) void layernorm_bf16_kernel(const float* __restrict__ in,
        const float* __restrict__ w, const float* __restrict__ b, ushort* __restrict__ out) {
    int row = blockIdx.x, t = threadIdx.x;
    float v = in[row * DM + t];
    float s = v, q = v * v;
#pragma unroll
    for (int o = 32; o >= 1; o >>= 1) { s += __shfl_xor(s, o); q += __shfl_xor(q, o); }
    __shared__ float red[8];
    int wid = t >> 6;
    if ((t & 63) == 0) { red[wid] = s; red[4 + wid] = q; }
    __syncthreads();
    s = red[0] + red[1] + red[2] + red[3];
    q = red[4] + red[5] + red[6] + red[7];
    float mu = s * (1.0f / DM);
    float var = q * (1.0f / DM) - mu * mu;
    float rs = rsqrtf(var + 1e-5f);
    out[row * DM + t] = f2bf((v - mu) * rs * w[t] + b[t]);
}

// ---- bf16 MFMA GEMM: C[M,N] = A[M,K] @ W[N,K]^T ----
// MODE 0: bf16 out + bias; MODE 1: f32 out; MODE 2: f32 out += acc + bias
template<int BM, int BN, int WM, int WN, int MODE>
__global__ __launch_bounds__(256) void mfma_gemm_kernel(
        const ushort* __restrict__ A, int lda,
        const ushort* __restrict__ W,
        const float* __restrict__ bias,
        ushort* __restrict__ Cb, float* __restrict__ Cf, int ldc, int K) {
    constexpr int FM = BM / WM / 16;
    constexpr int FN = BN / WN / 16;
    __shared__ __align__(16) char smem[(BM + BN) * 128];
    const int tid = threadIdx.x;
    const int l = tid & 63, w = tid >> 6;
    const int wr = w / WN, wc = w % WN;
    const int bm = blockIdx.x * BM, bn = blockIdx.y * BN;
    const int ldw = K;

    f32x4 acc[FM][FN] = {};

    for (int k0 = 0; k0 < K; k0 += 64) {
#pragma unroll
        for (int i = 0; i < (BM * 128 / 16) / 256; i++) {
            int lin = (i * 256 + tid) * 16;
            int q = lin ^ (((lin >> 7) & 7) << 4);
            g2lds16(A + (size_t)(bm + (q >> 7)) * lda + k0 + ((q & 127) >> 1), smem + lin);
        }
#pragma unroll
        for (int i = 0; i < (BN * 128 / 16) / 256; i++) {
            int lin = (i * 256 + tid) * 16;
            int q = lin ^ (((lin >> 7) & 7) << 4);
            g2lds16(W + (size_t)(bn + (q >> 7)) * ldw + k0 + ((q & 127) >> 1),
                    smem + BM * 128 + lin);
        }
        __syncthreads();
        const int rl = l & 15;
        const int kb0 = ((l >> 4) << 3) * 2;
#pragma unroll
        for (int kk = 0; kk < 2; kk++) {
            short8 af[FM], bfr[FN];
#pragma unroll
            for (int m = 0; m < FM; m++) {
                int off = (wr * (BM / WM) + m * 16 + rl) * 128 + kk * 64 + kb0;
                off ^= ((off >> 7) & 7) << 4;
                af[m] = *(const short8*)(smem + off);
            }
#pragma unroll
            for (int n = 0; n < FN; n++) {
                int off = (wc * (BN / WN) + n * 16 + rl) * 128 + kk * 64 + kb0;
                off ^= ((off >> 7) & 7) << 4;
                bfr[n] = *(const short8*)(smem + BM * 128 + off);
            }
#pragma unroll
            for (int m = 0; m < FM; m++)
#pragma unroll
                for (int n = 0; n < FN; n++)
                    acc[m][n] = __builtin_amdgcn_mfma_f32_16x16x32_bf16(
                        af[m], bfr[n], acc[m][n], 0, 0, 0);
        }
        __syncthreads();
    }

    const int row0 = bm + wr * (BM / WM) + ((l >> 4) << 2);
    const int col0 = bn + wc * (BN / WN) + (l & 15);
#pragma unroll
    for (int m = 0; m < FM; m++) {
#pragma unroll
        for (int n = 0; n < FN; n++) {
            int col = col0 + n * 16;
            float bv = (MODE == 1) ? 0.f : bias[col];
#pragma unroll
            for (int r = 0; r < 4; r++) {
                size_t idx = (size_t)(row0 + m * 16 + r) * ldc + col;
                float v = acc[m][n][r];
                if (MODE == 0) Cb[idx] = f2bf(v + bv);
                else if (MODE == 1) Cf[idx] = v;
                else Cf[idx] += v + bv;
            }
        }
    }
}

// depthwise causal conv (K=4) + SiLU; xz bf16 (ld 1024, cols 0..511) -> u bf16
__global__ __launch_bounds__(256) void conv_silu_kernel(const ushort* __restrict__ xz,
        const float* __restrict__ cw, const float* __restrict__ cb, ushort* __restrict__ u) {
    int t = blockIdx.x * 256 + threadIdx.x;   // MR*DI/8 threads
    int d8 = (t & 63) << 3;
    int m = t >> 6;
    int l = m & (LL - 1);
    const short8 zr = {0, 0, 0, 0, 0, 0, 0, 0};
    const size_t base = (size_t)m * 1024 + d8;
    short8 r3 = *(const short8*)(xz + base);
    short8 r2 = (l >= 1) ? *(const short8*)(xz + base - 1024) : zr;
    short8 r1 = (l >= 2) ? *(const short8*)(xz + base - 2048) : zr;
    short8 r0 = (l >= 3) ? *(const short8*)(xz + base - 3072) : zr;
    short8 o;
#pragma unroll
    for (int j = 0; j < 8; j++) {
        int d = d8 + j;
        float4 w4 = *reinterpret_cast<const float4*>(&cw[d * 4]);
        float a = cb[d] + w4.w * bf2f((ushort)r3[j]);
        a += w4.z * bf2f((ushort)r2[j]);
        a += w4.y * bf2f((ushort)r1[j]);
        a += w4.x * bf2f((ushort)r0[j]);
        o[j] = (short)f2bf(silu_f(a));
    }
    *(short8*)(u + (size_t)m * DI + d8) = o;
}

// ---- chunked parallel scan; u bf16, x_dbl f32 (ld 64) staged in LDS ----
// delta[m][d] = softplus( x_dbl[m][0..15] . dtw[d][:] + dtb[d] ) inline
// One block = one (b,c) chunk, 256 threads = one d-half.
// Phase 1: chunk state S (from h=0) and sdv = sum(delta).
__global__ __launch_bounds__(256, 4) void scan_phase1_kernel(
        const ushort* __restrict__ u, const float* __restrict__ x_dbl,
        const float* __restrict__ A_log,
        const float* __restrict__ dtw, const float* __restrict__ dtb,
        float* __restrict__ sdv, float* __restrict__ Sbuf) {
    __shared__ __align__(16) float xs[CLEN * 64];
    const int tid = threadIdx.x;
    const int bc = blockIdx.x >> 1;
    const int d = ((blockIdx.x & 1) << 8) + tid;
    const int c = bc & (NCHUNK - 1);
    const int b = bc >> 6;
    const int m0 = b * LL + c * CLEN;
    // stage chunk's x_dbl slab (CLEN x 64 floats = 4 KB)
    *reinterpret_cast<float4*>(&xs[tid * 4]) =
        *reinterpret_cast<const float4*>(&x_dbl[(size_t)m0 * 64 + tid * 4]);

    float Aval[DS], h[DS], wreg[DR];
#pragma unroll
    for (int q = 0; q < 4; q++) {
        float4 a4 = *reinterpret_cast<const float4*>(&A_log[d * DS + q * 4]);
        Aval[q*4+0] = -__expf(a4.x); Aval[q*4+1] = -__expf(a4.y);
        Aval[q*4+2] = -__expf(a4.z); Aval[q*4+3] = -__expf(a4.w);
        float4 w4 = *reinterpret_cast<const float4*>(&dtw[d * DR + q * 4]);
        wreg[q*4] = w4.x; wreg[q*4+1] = w4.y; wreg[q*4+2] = w4.z; wreg[q*4+3] = w4.w;
    }
    float dbv = dtb[d];
#pragma unroll
    for (int n = 0; n < DS; n++) h[n] = 0.f;
    const ushort* up = u + (size_t)m0 * DI + d;
    float sd = 0.f;
    __syncthreads();
    float uv = bf2f(up[0]);
    for (int t = 0; t < CLEN; t++) {
        float uvn = (t + 1 < CLEN) ? bf2f(up[(size_t)(t + 1) * DI]) : 0.f;
        const float* xr = &xs[t * 64];
        float p0 = dbv, p1 = 0.f, p2 = 0.f, p3 = 0.f;
#pragma unroll
        for (int k = 0; k < 4; k++) {
            p0 += wreg[k] * xr[k];
            p1 += wreg[4 + k] * xr[4 + k];
            p2 += wreg[8 + k] * xr[8 + k];
            p3 += wreg[12 + k] * xr[12 + k];
        }
        float z = (p0 + p1) + (p2 + p3);
        float dv = (z > 20.0f) ? z : __logf(1.0f + __expf(z));
        sd += dv;
        float du = dv * uv;
#pragma unroll
        for (int n = 0; n < DS; n++) {
            float dA = __expf(dv * Aval[n]);
            h[n] = dA * h[n] + du * xr[16 + n];
        }
        uv = uvn;
    }
    size_t base = ((size_t)((b * NCHUNK + c) * DI + d)) * DS;
#pragma unroll
    for (int q = 0; q < 4; q++)
        *reinterpret_cast<float4*>(&Sbuf[base + q * 4]) =
            make_float4(h[q*4], h[q*4+1], h[q*4+2], h[q*4+3]);
    sdv[(b * NCHUNK + c) * DI + d] = sd;
}

// Phase 2: per (b,d,n) thread; P_c = exp(A*sdv_c); Sbuf[c] overwritten with hinit.
__global__ __launch_bounds__(256) void scan_phase2_kernel(
        const float* __restrict__ sdv, const float* __restrict__ A_log,
        float* __restrict__ Sbuf) {
    int gid = blockIdx.x * 256 + threadIdx.x;
    int dn = gid & (DI * DS - 1);
    int b = gid >> 13;
    int n = dn & 15, d = dn >> 4;
    float Aval = -__expf(A_log[d * DS + n]);
    size_t idx0 = (size_t)b * NCHUNK * DI * DS + dn;
    const size_t stride = (size_t)DI * DS;
    int sb0 = b * NCHUNK * DI + d;
    float h = 0.f;
    float Sc = Sbuf[idx0];
    float sd = sdv[sb0];
    for (int c = 0; c < NCHUNK; c++) {
        size_t idx = idx0 + (size_t)c * stride;
        float Sn = 0.f, sdn = 0.f;
        if (c + 1 < NCHUNK) {
            Sn = Sbuf[idx + stride];
            sdn = sdv[sb0 + (c + 1) * DI];
        }
        float Pc = __expf(Aval * sd);
        Sbuf[idx] = h;
        h = Pc * h + Sc;
        Sc = Sn; sd = sdn;
    }
}

// Phase 3 + fused gate: replay chunk from hinit, y = scan_y * silu(res), bf16 out
__global__ __launch_bounds__(256, 4) void scan_phase3_kernel(
        const ushort* __restrict__ u, const float* __restrict__ x_dbl,
        const float* __restrict__ A_log,
        const float* __restrict__ dtw, const float* __restrict__ dtb,
        const float* __restrict__ Dp, const float* __restrict__ Sbuf,
        const ushort* __restrict__ xz, ushort* __restrict__ y) {
    __shared__ __align__(16) float xs[CLEN * 64];
    const int tid = threadIdx.x;
    const int bc = blockIdx.x >> 1;
    const int d = ((blockIdx.x & 1) << 8) + tid;
    const int c = bc & (NCHUNK - 1);
    const int b = bc >> 6;
    const int m0 = b * LL + c * CLEN;
    *reinterpret_cast<float4*>(&xs[tid * 4]) =
        *reinterpret_cast<const float4*>(&x_dbl[(size_t)m0 * 64 + tid * 4]);

    float Aval[DS], h[DS], wreg[DR];
#pragma unroll
    for (int q = 0; q < 4; q++) {
        float4 a4 = *reinterpret_cast<const float4*>(&A_log[d * DS + q * 4]);
        Aval[q*4+0] = -__expf(a4.x); Aval[q*4+1] = -__expf(a4.y);
        Aval[q*4+2] = -__expf(a4.z); Aval[q*4+3] = -__expf(a4.w);
        float4 w4 = *reinterpret_cast<const float4*>(&dtw[d * DR + q * 4]);
        wreg[q*4] = w4.x; wreg[q*4+1] = w4.y; wreg[q*4+2] = w4.z; wreg[q*4+3] = w4.w;
    }
    float dbv = dtb[d];
    size_t base = ((size_t)((b * NCHUNK + c) * DI + d)) * DS;
#pragma unroll
    for (int q = 0; q < 4; q++) {
        float4 h4 = *reinterpret_cast<const float4*>(&Sbuf[base + q * 4]);
        h[q*4] = h4.x; h[q*4+1] = h4.y; h[q*4+2] = h4.z; h[q*4+3] = h4.w;
    }
    float Dval = Dp[d];
    const ushort* up = u + (size_t)m0 * DI + d;
    const ushort* rp = xz + (size_t)m0 * 1024 + 512 + d;
    ushort* yp = y + (size_t)m0 * DI + d;
    __syncthreads();
    float uv = bf2f(up[0]);
    float rv = bf2f(rp[0]);
    for (int t = 0; t < CLEN; t++) {
        float uvn = 0.f, rvn = 0.f;
        if (t + 1 < CLEN) {
            uvn = bf2f(up[(size_t)(t + 1) * DI]);
            rvn = bf2f(rp[(size_t)(t + 1) * 1024]);
        }
        const float* xr = &xs[t * 64];
        float p0 = dbv, p1 = 0.f, p2 = 0.f, p3 = 0.f;
#pragma unroll
        for (int k = 0; k < 4; k++) {
            p0 += wreg[k] * xr[k];
            p1 += wreg[4 + k] * xr[4 + k];
            p2 += wreg[8 + k] * xr[8 + k];
            p3 += wreg[12 + k] * xr[12 + k];
        }
        float z = (p0 + p1) + (p2 + p3);
        float dv = (z > 20.0f) ? z : __logf(1.0f + __expf(z));
        float du = dv * uv;
        float a0 = 0.f, a1 = 0.f, a2 = 0.f, a3 = 0.f;
#pragma unroll
        for (int j = 0; j < 4; j++) {
            {
                int n = j;
                float dA = __expf(dv * Aval[n]);
                h[n] = dA * h[n] + du * xr[16 + n];
                a0 += h[n] * xr[32 + n];
            }
            {
                int n = 4 + j;
                float dA = __expf(dv * Aval[n]);
                h[n] = dA * h[n] + du * xr[16 + n];
                a1 += h[n] * xr[32 + n];
            }
            {
                int n = 8 + j;
                float dA = __expf(dv * Aval[n]);
                h[n] = dA * h[n] + du * xr[16 + n];
                a2 += h[n] * xr[32 + n];
            }
            {
                int n = 12 + j;
                float dA = __expf(dv * Aval[n]);
                h[n] = dA * h[n] + du * xr[16 + n];
                a3 += h[n] * xr[32 + n];
            }
        }
        float acc = ((a0 + a1) + (a2 + a3)) + Dval * uv;
        yp[(size_t)t * DI] = f2bf(acc * silu_f(rv));
        uv = uvn; rv = rvn;
    }
}

// pool stage 1: partial[(b*8+slice)][dm] = sum over 128 l's
__global__ __launch_bounds__(256) void pool_partial_kernel(const ushort* __restrict__ ln,
                                                           float* __restrict__ partial) {
    int bs = blockIdx.x;            // 0..63
    int b = bs >> 3, sl = bs & 7;
    int t = threadIdx.x;            // dm
    int l0 = sl * 128;
    float s = 0.f;
    for (int l = 0; l < 128; l++) s += bf2f(ln[(size_t)(b * LL + l0 + l) * DM + t]);
    partial[(bs << 8) + t] = s;
}

__global__ void cls_kernel(const float* __restrict__ partial, const float* __restrict__ cw,
                           const float* __restrict__ cb, float* __restrict__ out) {
    int t = threadIdx.x;
    if (t >= NB * NC) return;
    int b = t / NC, c = t % NC;
    float s = 0.f;
    for (int k = 0; k < DM; k++) {
        float p = 0.f;
#pragma unroll
        for (int sl = 0; sl < 8; sl++) p += partial[((b * 8 + sl) << 8) + k];
        s += p * cw[c * DM + k];
    }
    out[t] = cb[c] + s * (1.0f / LL);
}

extern "C" void kernel_launch(void* const* d_in, const int* in_sizes, int n_in,
                              void* d_out, int out_size, void* d_ws, size_t ws_size,
                              hipStream_t stream) {
    const float* x       = (const float*)d_in[0];
    const float* input_w = (const float*)d_in[1];
    const float* input_b = (const float*)d_in[2];
    const float* ln_w    = (const float*)d_in[3];
    const float* ln_b    = (const float*)d_in[4];
    const float* ipw     = (const float*)d_in[5];
    const float* ipb     = (const float*)d_in[6];
    const float* cw      = (const float*)d_in[7];
    const float* cb      = (const float*)d_in[8];
    const float* xpw     = (const float*)d_in[9];
    const float* dtw     = (const float*)d_in[10];
    const float* dtb     = (const float*)d_in[11];
    const float* A_log   = (const float*)d_in[12];
    const float* Dp      = (const float*)d_in[13];
    const float* opw     = (const float*)d_in[14];
    const float* opb     = (const float*)d_in[15];
    const float* norm_w  = (const float*)d_in[16];
    const float* norm_b  = (const float*)d_in[17];
    const float* cls_w   = (const float*)d_in[18];
    const float* cls_b   = (const float*)d_in[19];
    float* out = (float*)d_out;
    float* ws = (float*)d_ws;

    float*  hres   = ws;                                   // MR*DM f32
    ushort* xz     = (ushort*)(hres + (size_t)MR * DM);    // MR*1024 bf16
    ushort* ub     = xz + (size_t)MR * 1024;               // MR*DI bf16
    float*  x_dbl  = (float*)(ub + (size_t)MR * DI);       // MR*64 f32
    float*  sdvb   = x_dbl + (size_t)MR * 64;              // NB*NCHUNK*DI f32
    float*  Sbuf   = sdvb + (size_t)NB * NCHUNK * DI;      // NB*NCHUNK*DI*DS f32
    float*  partial= Sbuf + (size_t)NB * NCHUNK * DI * DS; // 64*256 f32
    ushort* ygate  = (ushort*)(partial + 64 * 256);        // MR*DI bf16
    ushort* hln    = ygate + (size_t)MR * DI;              // MR*DM bf16
    ushort* ipw_b  = hln + (size_t)MR * DM;                // IPW_N
    ushort* xpw_b  = ipw_b + IPW_N;                        // XPW_N
    ushort* opw_b  = xpw_b + XPW_N;                        // OPW_N

    convert_weights_kernel<<<(IPW_N + XPW_N + OPW_N) / 256, 256, 0, stream>>>(
        ipw, xpw, opw, ipw_b, xpw_b, opw_b);
    input_proj_kernel<<<MR * DM / 256, 256, 0, stream>>>(x, input_w, input_b, hres);

    for (int i = 0; i < NL; i++) {
        layernorm_bf16_kernel<<<MR, 256, 0, stream>>>(hres, ln_w + i * DM, ln_b + i * DM, hln);
        mfma_gemm_kernel<128, 128, 2, 2, 0><<<dim3(MR / 128, 1024 / 128), 256, 0, stream>>>(
            hln, DM, ipw_b + (size_t)i * 2 * DI * DM, ipb + (size_t)i * 2 * DI,
            xz, nullptr, 1024, DM);
        conv_silu_kernel<<<MR * DI / 8 / 256, 256, 0, stream>>>(xz, cw + i * DI * DC, cb + i * DI, ub);
        mfma_gemm_kernel<64, 64, 4, 1, 1><<<dim3(MR / 64, 1), 256, 0, stream>>>(
            ub, DI, xpw_b + (size_t)i * 64 * DI, nullptr, nullptr, x_dbl, 64, DI);
        scan_phase1_kernel<<<NB * NCHUNK * DI / 256, 256, 0, stream>>>(
            ub, x_dbl, A_log + i * DI * DS, dtw + i * DI * DR, dtb + i * DI, sdvb, Sbuf);
        scan_phase2_kernel<<<NB * DI * DS / 256, 256, 0, stream>>>(
            sdvb, A_log + i * DI * DS, Sbuf);
        scan_phase3_kernel<<<NB * NCHUNK * DI / 256, 256, 0, stream>>>(
            ub, x_dbl, A_log + i * DI * DS, dtw + i * DI * DR, dtb + i * DI,
            Dp + i * DI, Sbuf, xz, ygate);
        mfma_gemm_kernel<64, 128, 2, 2, 2><<<dim3(MR / 64, DM / 128), 256, 0, stream>>>(
            ygate, DI, opw_b + (size_t)i * DM * DI, opb + (size_t)i * DM,
            nullptr, hres, DM, DI);
    }

    layernorm_bf16_kernel<<<MR, 256, 0, stream>>>(hres, norm_w, norm_b, hln);
    pool_partial_kernel<<<64, 256, 0, stream>>>(hln, partial);
    cls_kernel<<<1, 128, 0, stream>>>(partial, cls_w, cls_b, out);
}